// Round 12
// baseline (177.177 us; speedup 1.0000x reference)
//
#include <hip/hip_runtime.h>
#include <stdint.h>

#define B_ 4
#define C_ 256
#define CH_ 128
#define HW_ 4096
#define L2E 1.44269504f
#define SHIFT_L2 14.4269504f   // 10.0 * log2(e): fixed softmax shift (shift-invariant)

typedef __bf16 bf16;
typedef __bf16 v8bf __attribute__((ext_vector_type(8)));
typedef __bf16 v4bf __attribute__((ext_vector_type(4)));
typedef float v4f __attribute__((ext_vector_type(4)));
struct f4 { float x, y, z, w; };
struct f2 { float x, y; };

#define GAS __attribute__((address_space(1)))
#define LAS __attribute__((address_space(3)))

__device__ __forceinline__ void async_copy16(const void* gptr, void* lptr) {
  __builtin_amdgcn_global_load_lds((GAS void*)gptr, (LAS void*)lptr, 16, 0, 0);
}

// ---------------------------------------------------------------------------
// wconv: convert Wq|Wk|Wv to bf16 ONCE (0.26 MB). (R8, kept: +4us)
// ---------------------------------------------------------------------------
__global__ __launch_bounds__(256)
void wconv_kernel(const float* __restrict__ Wq, const float* __restrict__ Wk,
                  const float* __restrict__ Wv, bf16* __restrict__ Wb)
{
  int i = blockIdx.x * 256 + threadIdx.x;   // 32768 threads x 4 elements
  int idx = i * 4;
  f4 v;
  if (idx < 32768)       v = *(const f4*)&Wq[idx];
  else if (idx < 65536)  v = *(const f4*)&Wk[idx - 32768];
  else                   v = *(const f4*)&Wv[idx - 65536];
  v4bf o;
  o[0] = (bf16)v.x; o[1] = (bf16)v.y; o[2] = (bf16)v.z; o[3] = (bf16)v.w;
  *(v4bf*)&Wb[idx] = o;
}

// ---------------------------------------------------------------------------
// Projection — R9 version (swizzled Xt staging, bf16 weights, b64 Ds writes).
// Proj theories falsified: traffic (R17), weight-cvt (R20, +4us), LDS
// conflicts (R21, null).
// ---------------------------------------------------------------------------
#define XSTRIDE 280              // els; 560 B = 140 dw; 16B-aligned rows

__global__ __launch_bounds__(512)
void proj_kernel(const float* __restrict__ a, const float* __restrict__ p,
                 const bf16* __restrict__ Wb,
                 const float* __restrict__ bq, const float* __restrict__ bk,
                 const float* __restrict__ bv,
                 bf16* __restrict__ Qt, bf16* __restrict__ Kt, bf16* __restrict__ Vn)
{
  __shared__ bf16 Xt[64 * XSTRIDE];   // 35840 B
  __shared__ bf16 Ds[9216];           // 18432 B -> 54272 total, 3 blocks/CU

  const int t = threadIdx.x;
  const int lane = t & 63;
  const int w = t >> 6;
  const int l15 = lane & 15;
  const int q = lane >> 4;

  const int s0 = blockIdx.x * 64;
  const int b = blockIdx.y;
  const int z = blockIdx.z;          // 0:Q 1:K 2:V0 3:V1

  const float* X = (z == 0) ? a : p;
  const bf16* W; const float* bias;
  if (z == 0)      { W = Wb;         bias = bq; }
  else if (z == 1) { W = Wb + 32768; bias = bk; }
  else             { W = Wb + 65536 + (z - 2) * 32768; bias = bv + (z - 2) * 128; }

  const float* Xb = X + ((size_t)b * C_) * HW_;
  #pragma unroll
  for (int j = 0; j < 4; ++j) {
    int linear = t + 512 * j;          // [0,2048): 16 s-quads * 128 cp
    int sq = linear & 15;
    int cp = linear >> 4;
    int s = sq * 4;
    int cps = cp ^ ((sq & 7) << 2);    // dword-granular XOR swizzle
    f4 x0 = *(const f4*)&Xb[(size_t)(2 * cp) * HW_ + s0 + s];
    f4 x1 = *(const f4*)&Xb[(size_t)(2 * cp + 1) * HW_ + s0 + s];
    const float* x0p = &x0.x; const float* x1p = &x1.x;
    #pragma unroll
    for (int k = 0; k < 4; ++k) {
      unsigned short u0 = __builtin_bit_cast(unsigned short, (bf16)x0p[k]);
      unsigned short u1 = __builtin_bit_cast(unsigned short, (bf16)x1p[k]);
      *(unsigned int*)&Xt[(s + k) * XSTRIDE + 2 * cps] =
          (unsigned int)u0 | ((unsigned int)u1 << 16);
    }
  }

  v8bf Af[8];
  const bf16* Wrow = W + (size_t)(16 * w + l15) * C_;
  #pragma unroll
  for (int kk = 0; kk < 8; ++kk)
    Af[kk] = *(const v8bf*)&Wrow[kk * 32 + q * 8];

  f4 bb = *(const f4*)&bias[16 * w + 4 * q];
  const float* bbp = &bb.x;

  __syncthreads();

  v4f acc[4];
  #pragma unroll
  for (int ns = 0; ns < 4; ++ns) { v4f zz = {0.f, 0.f, 0.f, 0.f}; acc[ns] = zz; }
  #pragma unroll
  for (int ns = 0; ns < 4; ++ns) {
    const int rx = 16 * ((4 * ns + (l15 >> 2)) & 7);
    const char* rowp = (const char*)Xt + (size_t)(16 * ns + l15) * (XSTRIDE * 2);
    #pragma unroll
    for (int kk = 0; kk < 8; ++kk) {
      v8bf Bf = *(const v8bf*)(rowp + ((kk * 64 + q * 16) ^ rx));
      acc[ns] = __builtin_amdgcn_mfma_f32_16x16x32_bf16(Af[kk], Bf, acc[ns], 0, 0, 0);
    }
  }

  if (z < 2) {
    #pragma unroll
    for (int ns = 0; ns < 4; ++ns) {
      v4bf pp;
      #pragma unroll
      for (int r = 0; r < 4; ++r) pp[r] = (bf16)(acc[ns][r] + bbp[r]);
      *(v4bf*)&Ds[(16 * ns + l15) * 144 + 16 * w + 4 * q] = pp;   // ds_write_b64
    }
    __syncthreads();
    bf16* dst = (z == 0) ? Qt : Kt;
    #pragma unroll
    for (int i = 0; i < 2; ++i) {
      int idx = t + 512 * i;
      int s = idx >> 4, ch = (idx & 15) * 8;
      *(v8bf*)&dst[((size_t)b * HW_ + s0 + s) * CH_ + ch] = *(const v8bf*)&Ds[s * 144 + ch];
    }
  } else {
    int o0 = (z - 2) * 128;
    #pragma unroll
    for (int ns = 0; ns < 4; ++ns)
      #pragma unroll
      for (int r = 0; r < 4; ++r) {
        int pos = 32 * (ns >> 1) + 8 * (l15 >> 2) + 4 * (ns & 1) + (l15 & 3);
        Ds[(16 * w + 4 * q + r) * 72 + pos] = (bf16)(acc[ns][r] + bbp[r]);
      }
    __syncthreads();
    #pragma unroll
    for (int i = 0; i < 2; ++i) {
      int idx = t + 512 * i;
      int o = idx >> 3, ch = (idx & 7) * 8;
      *(v8bf*)&Vn[((size_t)b * C_ + o0 + o) * HW_ + s0 + ch] = *(const v8bf*)&Ds[o * 72 + ch];
    }
  }
}

// ---------------------------------------------------------------------------
// Flash attention — R0/R4 core verbatim, NORMAL Op stores. R11 lesson
// (GLOBAL): __builtin_nontemporal_store on gfx950 is a write-around store —
// DRAM updated, existing L2 line left STALE; any consumer kernel (or host)
// whose line is L2-resident reads garbage. NT stores must never target
// buffers read by later kernels. NT *loads* are safe (coherent; only change
// allocation priority).
// ---------------------------------------------------------------------------
#define LDS_V 16640
#define TSTRIDE 52
#define TREGION 13312            // 256 rows * 52 els
#define LDS_TOTAL 53248

__global__ __launch_bounds__(256, 2)
void attn_kernel(const bf16* __restrict__ Qt, const bf16* __restrict__ Kt,
                 const bf16* __restrict__ Vn, const float* __restrict__ a,
                 float* __restrict__ out, bf16* __restrict__ Op,
                 float* __restrict__ Ls, int nsplit)
{
  extern __shared__ char smem[];
  const int t = threadIdx.x;
  const int lane = t & 63;
  const int w = t >> 6;        // 0..3
  const int l15 = lane & 15;
  const int q = lane >> 4;
  const int b = blockIdx.y;
  const int sp = blockIdx.z;
  const int m0 = blockIdx.x * 128;

  v8bf Qf[2][4];
  #pragma unroll
  for (int s = 0; s < 2; ++s) {
    const bf16* qrow = Qt + ((size_t)b * HW_ + m0 + 32 * w + 16 * s + l15) * CH_;
    #pragma unroll
    for (int kk = 0; kk < 4; ++kk)
      Qf[s][kk] = *(const v8bf*)&qrow[kk * 32 + q * 8];
  }

  v4f O[2][16];
  #pragma unroll
  for (int s = 0; s < 2; ++s)
    #pragma unroll
    for (int cs = 0; cs < 16; ++cs) { v4f zz = {0.f, 0.f, 0.f, 0.f}; O[s][cs] = zz; }
  float lsum[2] = {0.f, 0.f};

  const bf16* Kb = Kt + (size_t)b * HW_ * CH_;
  const bf16* Vb = Vn + (size_t)b * C_ * HW_;

  const int NT = 64 / nsplit;
  const int t0 = sp * NT;

  auto stageK = [&](int n0) {
    #pragma unroll
    for (int j = 0; j < 4; ++j) {
      int i = 4 * j + w;
      async_copy16(Kb + ((size_t)(n0 + i + 16 * q)) * CH_ + l15 * 8, smem + i * 1040);
    }
  };
  auto stageV = [&](int n0) {
    #pragma unroll
    for (int j = 0; j < 8; ++j) {
      int i = 4 * j + w;
      async_copy16(Vb + ((size_t)(i + 32 * (lane >> 3))) * HW_ + n0 + (lane & 7) * 8,
                   smem + LDS_V + i * 1040);
    }
  };

  stageK(t0 * 64);
  stageV(t0 * 64);
  __syncthreads();

  for (int nt = 0; nt < NT; ++nt) {
    int n0 = (t0 + nt) * 64;

    // ---- S^T = K.Q^T : St[n-sub][m-sub], D row=n(4q+r), col=m(l15) ----
    v4f St[4][2];
    #pragma unroll
    for (int sub = 0; sub < 4; ++sub)
      #pragma unroll
      for (int s = 0; s < 2; ++s) { v4f zz = {0.f, 0.f, 0.f, 0.f}; St[sub][s] = zz; }
    #pragma unroll
    for (int sub = 0; sub < 4; ++sub)
      #pragma unroll
      for (int kk = 0; kk < 4; ++kk) {
        v8bf Kf = *(const v8bf*)(smem + l15 * 1040 + sub * 256 + kk * 64 + q * 16);
        St[sub][0] = __builtin_amdgcn_mfma_f32_16x16x32_bf16(Kf, Qf[0][kk], St[sub][0], 0, 0, 0);
        St[sub][1] = __builtin_amdgcn_mfma_f32_16x16x32_bf16(Kf, Qf[1][kk], St[sub][1], 0, 0, 0);
      }

    __syncthreads();                        // bar1: K reads done; V(t) DMA drained
    if (nt + 1 < NT) stageK(n0 + 64);       // K(t+1) overlaps softmax+PV

    // ---- in-register P pack: A-frag slot 4a+r of 32-block kk holds
    //      P[m=l15][n=32kk+16a+4q+r]; V stored with matching permutation ----
    v8bf Pf[2][2];
    #pragma unroll
    for (int s = 0; s < 2; ++s) {
      float ls = 0.f;
      #pragma unroll
      for (int kk = 0; kk < 2; ++kk)
        #pragma unroll
        for (int a2 = 0; a2 < 2; ++a2)
          #pragma unroll
          for (int r = 0; r < 4; ++r) {
            float pv = exp2f(St[2 * kk + a2][s][r] * L2E - SHIFT_L2);
            Pf[s][kk][4 * a2 + r] = (bf16)pv;
            ls += pv;
          }
      lsum[s] += ls;
    }

    // ---- PV: O[m][c], A=Pf (regs), B=V from LDS ----
    #pragma unroll
    for (int cs = 0; cs < 16; ++cs)
      #pragma unroll
      for (int kk = 0; kk < 2; ++kk) {
        v8bf Vf = *(const v8bf*)(smem + LDS_V +
                                 (16 * (cs & 1) + l15) * 1040 + (cs >> 1) * 128 + kk * 64 + q * 16);
        O[0][cs] = __builtin_amdgcn_mfma_f32_16x16x32_bf16(Pf[0][kk], Vf, O[0][cs], 0, 0, 0);
        O[1][cs] = __builtin_amdgcn_mfma_f32_16x16x32_bf16(Pf[1][kk], Vf, O[1][cs], 0, 0, 0);
      }

    __syncthreads();                        // bar2: V reads done; K(t+1) drained
    if (nt + 1 < NT) stageV(n0 + 64);       // V(t+1) overlaps next QK
  }

  // final l per m=l15 row: sum the 4 q-group partials
  float lfin[2];
  #pragma unroll
  for (int s = 0; s < 2; ++s) {
    float l = lsum[s];
    l += __shfl_xor(l, 16);
    l += __shfl_xor(l, 32);
    lfin[s] = l;
  }

  if (nsplit > 1 && lane < 16) {
    #pragma unroll
    for (int s = 0; s < 2; ++s)
      Ls[((size_t)sp * B_ + b) * HW_ + m0 + 32 * w + 16 * s + lane] = lfin[s];
  }

  // epilogue: O rows are m=16s+4q+r -> fetch 1/l via shuffle from lane 4q+r
  float linv[2][4];
  #pragma unroll
  for (int s = 0; s < 2; ++s)
    #pragma unroll
    for (int r = 0; r < 4; ++r)
      linv[s][r] = (nsplit == 1) ? 1.0f / __shfl(lfin[s], 4 * q + r) : 1.0f;

  bf16* T = (bf16*)smem;
  for (int round = 0; round < 2; ++round) {
    __syncthreads();
    if ((w >> 1) == round) {
      bf16* Tw = T + (w & 1) * TREGION;
      #pragma unroll
      for (int s = 0; s < 2; ++s)
        #pragma unroll
        for (int cs = 0; cs < 16; ++cs) {
          v4bf pp4;
          #pragma unroll
          for (int r = 0; r < 4; ++r) pp4[r] = (bf16)(O[s][cs][r] * linv[s][r]);
          *(v4bf*)&Tw[(16 * cs + l15) * TSTRIDE + 16 * s + 4 * q] = pp4;   // ds_write_b64, 8B-aligned
        }
    }
    __syncthreads();
    #pragma unroll
    for (int it = 0; it < 8; ++it) {
      int idx = t + 256 * it;
      int tt = idx >> 10;
      int c = (idx >> 2) & 255;
      int mc = idx & 3;
      int wavew = round * 2 + tt;
      int mg = m0 + 32 * wavew + mc * 8;
      const bf16* Trow = &T[tt * TREGION + c * TSTRIDE + mc * 8];
      v4bf lo = *(const v4bf*)&Trow[0];     // 8B-aligned pair (row base is 8B-aligned
      v4bf hi = *(const v4bf*)&Trow[4];     //  only: 104B rows; avoid b128)
      if (nsplit == 1) {
        size_t gi = ((size_t)b * C_ + c) * HW_ + mg;
        #pragma unroll
        for (int j2 = 0; j2 < 4; ++j2) out[gi + j2] = (float)lo[j2] + a[gi + j2];
        #pragma unroll
        for (int j2 = 0; j2 < 4; ++j2) out[gi + 4 + j2] = (float)hi[j2] + a[gi + 4 + j2];
      } else {
        size_t gi = (((size_t)sp * B_ + b) * C_ + c) * HW_ + mg;
        v8bf val;
        #pragma unroll
        for (int j2 = 0; j2 < 4; ++j2) { val[j2] = lo[j2]; val[4 + j2] = hi[j2]; }
        *(v8bf*)&Op[gi] = val;               // NORMAL store (NT store = stale-L2 hazard)
      }
    }
  }
}

// ---------------------------------------------------------------------------
// Combine — R24: NT LOADS only (coherent, evict-first allocation) for the
// write-once/read-once Op/Ls/a streams; NORMAL stores for out (host-read).
// 8-value chunks/thread.
// ---------------------------------------------------------------------------
__global__ __launch_bounds__(256)
void combine_kernel(const bf16* __restrict__ Op, const float* __restrict__ Ls,
                    const float* __restrict__ a, float* __restrict__ out, int nsplit)
{
  int idx = blockIdx.x * 256 + threadIdx.x;     // B*C*HW/8 threads
  int m8 = (idx & (HW_ / 8 - 1)) * 8;
  int bc = idx >> 9;                            // HW_/8 = 512
  int b = bc >> 8;

  float acc[8] = {0.f, 0.f, 0.f, 0.f, 0.f, 0.f, 0.f, 0.f};
  float Lt[8] = {0.f, 0.f, 0.f, 0.f, 0.f, 0.f, 0.f, 0.f};
  for (int s = 0; s < nsplit; ++s) {
    v8bf o = __builtin_nontemporal_load((const v8bf*)&Op[((size_t)s * B_ * C_ + bc) * HW_ + m8]);
    v4f l0 = __builtin_nontemporal_load((const v4f*)&Ls[((size_t)s * B_ + b) * HW_ + m8]);
    v4f l1 = __builtin_nontemporal_load((const v4f*)&Ls[((size_t)s * B_ + b) * HW_ + m8 + 4]);
    #pragma unroll
    for (int j = 0; j < 8; ++j) acc[j] += (float)o[j];
    #pragma unroll
    for (int j = 0; j < 4; ++j) { Lt[j] += l0[j]; Lt[4 + j] += l1[j]; }
  }
  size_t gi = (size_t)bc * HW_ + m8;
  v4f a0 = __builtin_nontemporal_load((const v4f*)&a[gi]);
  v4f a1 = __builtin_nontemporal_load((const v4f*)&a[gi + 4]);
  v4f o0, o1;
  #pragma unroll
  for (int j = 0; j < 4; ++j) {
    o0[j] = acc[j] / Lt[j] + a0[j];
    o1[j] = acc[4 + j] / Lt[4 + j] + a1[j];
  }
  *(v4f*)&out[gi] = o0;                     // NORMAL stores (host-read buffer)
  *(v4f*)&out[gi + 4] = o1;
}

extern "C" void kernel_launch(void* const* d_in, const int* in_sizes, int n_in,
                              void* d_out, int out_size, void* d_ws, size_t ws_size,
                              hipStream_t stream) {
  const float* a  = (const float*)d_in[0];
  const float* p  = (const float*)d_in[1];
  const float* Wq = (const float*)d_in[2];
  const float* bq = (const float*)d_in[3];
  const float* Wk = (const float*)d_in[4];
  const float* bk = (const float*)d_in[5];
  const float* Wv = (const float*)d_in[6];
  const float* bv = (const float*)d_in[7];
  float* out = (float*)d_out;

  bf16* Qt = (bf16*)d_ws;                        // 4 MB
  bf16* Kt = Qt + (size_t)B_ * HW_ * CH_;        // 4 MB
  bf16* Vn = Kt + (size_t)B_ * HW_ * CH_;        // 8 MB

  const size_t proj_bytes = 16777216ull;
  const size_t part_bytes = (size_t)B_ * C_ * HW_ * 2;   // 8 MB per split
  const size_t stat_bytes = (size_t)B_ * HW_ * 4;
  const size_t wb_bytes   = 131072ull * 2;               // bf16 Wq|Wk|Wv
  auto need = [&](int S) {
    return proj_bytes + (size_t)S * (part_bytes + stat_bytes) + wb_bytes;
  };

  int S;
  if      (ws_size >= need(4)) S = 4;            // S=8 regressed (R10): Op traffic
  else if (ws_size >= need(2)) S = 2;
  else                         S = 1;

  bf16* Op  = (bf16*)((char*)d_ws + proj_bytes);
  float* Ls = (float*)((char*)d_ws + proj_bytes + (size_t)S * part_bytes);
  bf16* Wb  = (bf16*)((char*)d_ws + proj_bytes + (size_t)S * (part_bytes + stat_bytes));

  wconv_kernel<<<128, 256, 0, stream>>>(Wq, Wk, Wv, Wb);

  dim3 pg(HW_ / 64, B_, 4);                      // R2/R9 ordering (measured best)
  proj_kernel<<<pg, 512, 0, stream>>>(a, p, Wb, bq, bk, bv, Qt, Kt, Vn);

  dim3 ag(HW_ / 128, B_, S);
  attn_kernel<<<ag, 256, LDS_TOTAL, stream>>>(Qt, Kt, Vn, a, out, Op, Ls, S);

  if (S > 1) {
    int nblk = (B_ * C_ * HW_ / 8) / 256;
    combine_kernel<<<nblk, 256, 0, stream>>>(Op, Ls, a, out, S);
  }
}

// Round 13
// 169.760 us; speedup vs baseline: 1.0437x; 1.0437x over previous
//
#include <hip/hip_runtime.h>
#include <stdint.h>

#define B_ 4
#define C_ 256
#define CH_ 128
#define HW_ 4096
#define L2E 1.44269504f
#define SHIFT_L2 14.4269504f   // 10.0 * log2(e): fixed softmax shift (shift-invariant)

typedef __bf16 bf16;
typedef __bf16 v8bf __attribute__((ext_vector_type(8)));
typedef __bf16 v4bf __attribute__((ext_vector_type(4)));
typedef float v4f __attribute__((ext_vector_type(4)));
struct f4 { float x, y, z, w; };
struct f2 { float x, y; };

#define GAS __attribute__((address_space(1)))
#define LAS __attribute__((address_space(3)))

__device__ __forceinline__ void async_copy16(const void* gptr, void* lptr) {
  __builtin_amdgcn_global_load_lds((GAS void*)gptr, (LAS void*)lptr, 16, 0, 0);
}

// ---------------------------------------------------------------------------
// wconv: convert Wq|Wk|Wv to bf16 ONCE (0.26 MB). (R8, kept: -4us total)
// ---------------------------------------------------------------------------
__global__ __launch_bounds__(256)
void wconv_kernel(const float* __restrict__ Wq, const float* __restrict__ Wk,
                  const float* __restrict__ Wv, bf16* __restrict__ Wb)
{
  int i = blockIdx.x * 256 + threadIdx.x;   // 32768 threads x 4 elements
  int idx = i * 4;
  f4 v;
  if (idx < 32768)       v = *(const f4*)&Wq[idx];
  else if (idx < 65536)  v = *(const f4*)&Wk[idx - 32768];
  else                   v = *(const f4*)&Wv[idx - 65536];
  v4bf o;
  o[0] = (bf16)v.x; o[1] = (bf16)v.y; o[2] = (bf16)v.z; o[3] = (bf16)v.w;
  *(v4bf*)&Wb[idx] = o;
}

// ---------------------------------------------------------------------------
// Projection — R9 version (swizzled Xt staging, bf16 weights, b64 Ds writes).
// Proj theories falsified: traffic (R17), weight-cvt (R20, -4us kept),
// LDS conflicts (R21, null).
// ---------------------------------------------------------------------------
#define XSTRIDE 280              // els; 560 B = 140 dw; 16B-aligned rows

__global__ __launch_bounds__(512)
void proj_kernel(const float* __restrict__ a, const float* __restrict__ p,
                 const bf16* __restrict__ Wb,
                 const float* __restrict__ bq, const float* __restrict__ bk,
                 const float* __restrict__ bv,
                 bf16* __restrict__ Qt, bf16* __restrict__ Kt, bf16* __restrict__ Vn)
{
  __shared__ bf16 Xt[64 * XSTRIDE];   // 35840 B
  __shared__ bf16 Ds[9216];           // 18432 B -> 54272 total, 3 blocks/CU

  const int t = threadIdx.x;
  const int lane = t & 63;
  const int w = t >> 6;
  const int l15 = lane & 15;
  const int q = lane >> 4;

  const int s0 = blockIdx.x * 64;
  const int b = blockIdx.y;
  const int z = blockIdx.z;          // 0:Q 1:K 2:V0 3:V1

  const float* X = (z == 0) ? a : p;
  const bf16* W; const float* bias;
  if (z == 0)      { W = Wb;         bias = bq; }
  else if (z == 1) { W = Wb + 32768; bias = bk; }
  else             { W = Wb + 65536 + (z - 2) * 32768; bias = bv + (z - 2) * 128; }

  const float* Xb = X + ((size_t)b * C_) * HW_;
  #pragma unroll
  for (int j = 0; j < 4; ++j) {
    int linear = t + 512 * j;          // [0,2048): 16 s-quads * 128 cp
    int sq = linear & 15;
    int cp = linear >> 4;
    int s = sq * 4;
    int cps = cp ^ ((sq & 7) << 2);    // dword-granular XOR swizzle
    f4 x0 = *(const f4*)&Xb[(size_t)(2 * cp) * HW_ + s0 + s];
    f4 x1 = *(const f4*)&Xb[(size_t)(2 * cp + 1) * HW_ + s0 + s];
    const float* x0p = &x0.x; const float* x1p = &x1.x;
    #pragma unroll
    for (int k = 0; k < 4; ++k) {
      unsigned short u0 = __builtin_bit_cast(unsigned short, (bf16)x0p[k]);
      unsigned short u1 = __builtin_bit_cast(unsigned short, (bf16)x1p[k]);
      *(unsigned int*)&Xt[(s + k) * XSTRIDE + 2 * cps] =
          (unsigned int)u0 | ((unsigned int)u1 << 16);
    }
  }

  v8bf Af[8];
  const bf16* Wrow = W + (size_t)(16 * w + l15) * C_;
  #pragma unroll
  for (int kk = 0; kk < 8; ++kk)
    Af[kk] = *(const v8bf*)&Wrow[kk * 32 + q * 8];

  f4 bb = *(const f4*)&bias[16 * w + 4 * q];
  const float* bbp = &bb.x;

  __syncthreads();

  v4f acc[4];
  #pragma unroll
  for (int ns = 0; ns < 4; ++ns) { v4f zz = {0.f, 0.f, 0.f, 0.f}; acc[ns] = zz; }
  #pragma unroll
  for (int ns = 0; ns < 4; ++ns) {
    const int rx = 16 * ((4 * ns + (l15 >> 2)) & 7);
    const char* rowp = (const char*)Xt + (size_t)(16 * ns + l15) * (XSTRIDE * 2);
    #pragma unroll
    for (int kk = 0; kk < 8; ++kk) {
      v8bf Bf = *(const v8bf*)(rowp + ((kk * 64 + q * 16) ^ rx));
      acc[ns] = __builtin_amdgcn_mfma_f32_16x16x32_bf16(Af[kk], Bf, acc[ns], 0, 0, 0);
    }
  }

  if (z < 2) {
    #pragma unroll
    for (int ns = 0; ns < 4; ++ns) {
      v4bf pp;
      #pragma unroll
      for (int r = 0; r < 4; ++r) pp[r] = (bf16)(acc[ns][r] + bbp[r]);
      *(v4bf*)&Ds[(16 * ns + l15) * 144 + 16 * w + 4 * q] = pp;   // ds_write_b64
    }
    __syncthreads();
    bf16* dst = (z == 0) ? Qt : Kt;
    #pragma unroll
    for (int i = 0; i < 2; ++i) {
      int idx = t + 512 * i;
      int s = idx >> 4, ch = (idx & 15) * 8;
      *(v8bf*)&dst[((size_t)b * HW_ + s0 + s) * CH_ + ch] = *(const v8bf*)&Ds[s * 144 + ch];
    }
  } else {
    int o0 = (z - 2) * 128;
    #pragma unroll
    for (int ns = 0; ns < 4; ++ns)
      #pragma unroll
      for (int r = 0; r < 4; ++r) {
        int pos = 32 * (ns >> 1) + 8 * (l15 >> 2) + 4 * (ns & 1) + (l15 & 3);
        Ds[(16 * w + 4 * q + r) * 72 + pos] = (bf16)(acc[ns][r] + bbp[r]);
      }
    __syncthreads();
    #pragma unroll
    for (int i = 0; i < 2; ++i) {
      int idx = t + 512 * i;
      int o = idx >> 3, ch = (idx & 7) * 8;
      *(v8bf*)&Vn[((size_t)b * C_ + o0 + o) * HW_ + s0 + ch] = *(const v8bf*)&Ds[o * 72 + ch];
    }
  }
}

// ---------------------------------------------------------------------------
// Flash attention — R0/R4 core verbatim, NORMAL Op stores. Session pitfalls
// (GLOBAL): (1) device-scope __threadfence in-loop = L2 writeback storm
// (R5, 4.6x slower); (2) __builtin_nontemporal_store = write-around, leaves
// L2-resident lines STALE for consumer kernels (R11, wrong results). NT
// loads are coherent but measured null-to-negative here (R12).
// ---------------------------------------------------------------------------
#define LDS_V 16640
#define TSTRIDE 52
#define TREGION 13312            // 256 rows * 52 els
#define LDS_TOTAL 53248

__global__ __launch_bounds__(256, 2)
void attn_kernel(const bf16* __restrict__ Qt, const bf16* __restrict__ Kt,
                 const bf16* __restrict__ Vn, const float* __restrict__ a,
                 float* __restrict__ out, bf16* __restrict__ Op,
                 float* __restrict__ Ls, int nsplit)
{
  extern __shared__ char smem[];
  const int t = threadIdx.x;
  const int lane = t & 63;
  const int w = t >> 6;        // 0..3
  const int l15 = lane & 15;
  const int q = lane >> 4;
  const int b = blockIdx.y;
  const int sp = blockIdx.z;
  const int m0 = blockIdx.x * 128;

  v8bf Qf[2][4];
  #pragma unroll
  for (int s = 0; s < 2; ++s) {
    const bf16* qrow = Qt + ((size_t)b * HW_ + m0 + 32 * w + 16 * s + l15) * CH_;
    #pragma unroll
    for (int kk = 0; kk < 4; ++kk)
      Qf[s][kk] = *(const v8bf*)&qrow[kk * 32 + q * 8];
  }

  v4f O[2][16];
  #pragma unroll
  for (int s = 0; s < 2; ++s)
    #pragma unroll
    for (int cs = 0; cs < 16; ++cs) { v4f zz = {0.f, 0.f, 0.f, 0.f}; O[s][cs] = zz; }
  float lsum[2] = {0.f, 0.f};

  const bf16* Kb = Kt + (size_t)b * HW_ * CH_;
  const bf16* Vb = Vn + (size_t)b * C_ * HW_;

  const int NT = 64 / nsplit;
  const int t0 = sp * NT;

  auto stageK = [&](int n0) {
    #pragma unroll
    for (int j = 0; j < 4; ++j) {
      int i = 4 * j + w;
      async_copy16(Kb + ((size_t)(n0 + i + 16 * q)) * CH_ + l15 * 8, smem + i * 1040);
    }
  };
  auto stageV = [&](int n0) {
    #pragma unroll
    for (int j = 0; j < 8; ++j) {
      int i = 4 * j + w;
      async_copy16(Vb + ((size_t)(i + 32 * (lane >> 3))) * HW_ + n0 + (lane & 7) * 8,
                   smem + LDS_V + i * 1040);
    }
  };

  stageK(t0 * 64);
  stageV(t0 * 64);
  __syncthreads();

  for (int nt = 0; nt < NT; ++nt) {
    int n0 = (t0 + nt) * 64;

    // ---- S^T = K.Q^T : St[n-sub][m-sub], D row=n(4q+r), col=m(l15) ----
    v4f St[4][2];
    #pragma unroll
    for (int sub = 0; sub < 4; ++sub)
      #pragma unroll
      for (int s = 0; s < 2; ++s) { v4f zz = {0.f, 0.f, 0.f, 0.f}; St[sub][s] = zz; }
    #pragma unroll
    for (int sub = 0; sub < 4; ++sub)
      #pragma unroll
      for (int kk = 0; kk < 4; ++kk) {
        v8bf Kf = *(const v8bf*)(smem + l15 * 1040 + sub * 256 + kk * 64 + q * 16);
        St[sub][0] = __builtin_amdgcn_mfma_f32_16x16x32_bf16(Kf, Qf[0][kk], St[sub][0], 0, 0, 0);
        St[sub][1] = __builtin_amdgcn_mfma_f32_16x16x32_bf16(Kf, Qf[1][kk], St[sub][1], 0, 0, 0);
      }

    __syncthreads();                        // bar1: K reads done; V(t) DMA drained
    if (nt + 1 < NT) stageK(n0 + 64);       // K(t+1) overlaps softmax+PV

    // ---- in-register P pack: A-frag slot 4a+r of 32-block kk holds
    //      P[m=l15][n=32kk+16a+4q+r]; V stored with matching permutation ----
    v8bf Pf[2][2];
    #pragma unroll
    for (int s = 0; s < 2; ++s) {
      float ls = 0.f;
      #pragma unroll
      for (int kk = 0; kk < 2; ++kk)
        #pragma unroll
        for (int a2 = 0; a2 < 2; ++a2)
          #pragma unroll
          for (int r = 0; r < 4; ++r) {
            float pv = exp2f(St[2 * kk + a2][s][r] * L2E - SHIFT_L2);
            Pf[s][kk][4 * a2 + r] = (bf16)pv;
            ls += pv;
          }
      lsum[s] += ls;
    }

    // ---- PV: O[m][c], A=Pf (regs), B=V from LDS ----
    #pragma unroll
    for (int cs = 0; cs < 16; ++cs)
      #pragma unroll
      for (int kk = 0; kk < 2; ++kk) {
        v8bf Vf = *(const v8bf*)(smem + LDS_V +
                                 (16 * (cs & 1) + l15) * 1040 + (cs >> 1) * 128 + kk * 64 + q * 16);
        O[0][cs] = __builtin_amdgcn_mfma_f32_16x16x32_bf16(Pf[0][kk], Vf, O[0][cs], 0, 0, 0);
        O[1][cs] = __builtin_amdgcn_mfma_f32_16x16x32_bf16(Pf[1][kk], Vf, O[1][cs], 0, 0, 0);
      }

    __syncthreads();                        // bar2: V reads done; K(t+1) drained
    if (nt + 1 < NT) stageV(n0 + 64);       // V(t+1) overlaps next QK
  }

  // final l per m=l15 row: sum the 4 q-group partials
  float lfin[2];
  #pragma unroll
  for (int s = 0; s < 2; ++s) {
    float l = lsum[s];
    l += __shfl_xor(l, 16);
    l += __shfl_xor(l, 32);
    lfin[s] = l;
  }

  if (nsplit > 1 && lane < 16) {
    #pragma unroll
    for (int s = 0; s < 2; ++s)
      Ls[((size_t)sp * B_ + b) * HW_ + m0 + 32 * w + 16 * s + lane] = lfin[s];
  }

  // epilogue: O rows are m=16s+4q+r -> fetch 1/l via shuffle from lane 4q+r
  float linv[2][4];
  #pragma unroll
  for (int s = 0; s < 2; ++s)
    #pragma unroll
    for (int r = 0; r < 4; ++r)
      linv[s][r] = (nsplit == 1) ? 1.0f / __shfl(lfin[s], 4 * q + r) : 1.0f;

  bf16* T = (bf16*)smem;
  for (int round = 0; round < 2; ++round) {
    __syncthreads();
    if ((w >> 1) == round) {
      bf16* Tw = T + (w & 1) * TREGION;
      #pragma unroll
      for (int s = 0; s < 2; ++s)
        #pragma unroll
        for (int cs = 0; cs < 16; ++cs) {
          v4bf pp4;
          #pragma unroll
          for (int r = 0; r < 4; ++r) pp4[r] = (bf16)(O[s][cs][r] * linv[s][r]);
          *(v4bf*)&Tw[(16 * cs + l15) * TSTRIDE + 16 * s + 4 * q] = pp4;   // ds_write_b64, 8B-aligned
        }
    }
    __syncthreads();
    #pragma unroll
    for (int it = 0; it < 8; ++it) {
      int idx = t + 256 * it;
      int tt = idx >> 10;
      int c = (idx >> 2) & 255;
      int mc = idx & 3;
      int wavew = round * 2 + tt;
      int mg = m0 + 32 * wavew + mc * 8;
      const bf16* Trow = &T[tt * TREGION + c * TSTRIDE + mc * 8];
      v4bf lo = *(const v4bf*)&Trow[0];     // 8B-aligned pair (row base is 8B-aligned
      v4bf hi = *(const v4bf*)&Trow[4];     //  only: 104B rows; avoid b128)
      if (nsplit == 1) {
        size_t gi = ((size_t)b * C_ + c) * HW_ + mg;
        #pragma unroll
        for (int j2 = 0; j2 < 4; ++j2) out[gi + j2] = (float)lo[j2] + a[gi + j2];
        #pragma unroll
        for (int j2 = 0; j2 < 4; ++j2) out[gi + 4 + j2] = (float)hi[j2] + a[gi + 4 + j2];
      } else {
        size_t gi = (((size_t)sp * B_ + b) * C_ + c) * HW_ + mg;
        v8bf val;
        #pragma unroll
        for (int j2 = 0; j2 < 4; ++j2) { val[j2] = lo[j2]; val[4 + j2] = hi[j2]; }
        *(v8bf*)&Op[gi] = val;               // NORMAL store (NT store = stale-L2 hazard)
      }
    }
  }
}

// ---------------------------------------------------------------------------
// Combine — R0/R8 version exactly (4-value chunks, normal loads): the only
// delta from R12, which measured +7us vs R8. NT loads + 8-wide chunking
// falsified (R12).
// ---------------------------------------------------------------------------
__global__ __launch_bounds__(256)
void combine_kernel(const bf16* __restrict__ Op, const float* __restrict__ Ls,
                    const float* __restrict__ a, float* __restrict__ out, int nsplit)
{
  int idx = blockIdx.x * 256 + threadIdx.x;     // B*C*HW/4 threads
  int m4 = (idx & (HW_ / 4 - 1)) * 4;
  int bc = idx >> 10;                           // HW_/4 = 1024
  int b = bc >> 8;

  float a0 = 0.f, a1 = 0.f, a2 = 0.f, a3 = 0.f;
  float L0 = 0.f, L1 = 0.f, L2 = 0.f, L3 = 0.f;
  for (int s = 0; s < nsplit; ++s) {
    v4bf o = *(const v4bf*)&Op[((size_t)s * B_ * C_ + bc) * HW_ + m4];
    f4 lp = *(const f4*)&Ls[((size_t)s * B_ + b) * HW_ + m4];
    a0 += (float)o[0]; a1 += (float)o[1]; a2 += (float)o[2]; a3 += (float)o[3];
    L0 += lp.x; L1 += lp.y; L2 += lp.z; L3 += lp.w;
  }
  f4 av = *(const f4*)&a[(size_t)bc * HW_ + m4];
  f4 ov;
  ov.x = a0 / L0 + av.x;
  ov.y = a1 / L1 + av.y;
  ov.z = a2 / L2 + av.z;
  ov.w = a3 / L3 + av.w;
  *(f4*)&out[(size_t)bc * HW_ + m4] = ov;
}

extern "C" void kernel_launch(void* const* d_in, const int* in_sizes, int n_in,
                              void* d_out, int out_size, void* d_ws, size_t ws_size,
                              hipStream_t stream) {
  const float* a  = (const float*)d_in[0];
  const float* p  = (const float*)d_in[1];
  const float* Wq = (const float*)d_in[2];
  const float* bq = (const float*)d_in[3];
  const float* Wk = (const float*)d_in[4];
  const float* bk = (const float*)d_in[5];
  const float* Wv = (const float*)d_in[6];
  const float* bv = (const float*)d_in[7];
  float* out = (float*)d_out;

  bf16* Qt = (bf16*)d_ws;                        // 4 MB
  bf16* Kt = Qt + (size_t)B_ * HW_ * CH_;        // 4 MB
  bf16* Vn = Kt + (size_t)B_ * HW_ * CH_;        // 8 MB

  const size_t proj_bytes = 16777216ull;
  const size_t part_bytes = (size_t)B_ * C_ * HW_ * 2;   // 8 MB per split
  const size_t stat_bytes = (size_t)B_ * HW_ * 4;
  const size_t wb_bytes   = 131072ull * 2;               // bf16 Wq|Wk|Wv
  auto need = [&](int S) {
    return proj_bytes + (size_t)S * (part_bytes + stat_bytes) + wb_bytes;
  };

  int S;
  if      (ws_size >= need(4)) S = 4;            // S=8 regressed (R10): Op traffic
  else if (ws_size >= need(2)) S = 2;
  else                         S = 1;

  bf16* Op  = (bf16*)((char*)d_ws + proj_bytes);
  float* Ls = (float*)((char*)d_ws + proj_bytes + (size_t)S * part_bytes);
  bf16* Wb  = (bf16*)((char*)d_ws + proj_bytes + (size_t)S * (part_bytes + stat_bytes));

  wconv_kernel<<<128, 256, 0, stream>>>(Wq, Wk, Wv, Wb);

  dim3 pg(HW_ / 64, B_, 4);                      // R2/R9 ordering (measured best)
  proj_kernel<<<pg, 512, 0, stream>>>(a, p, Wb, bq, bk, bv, Qt, Kt, Vn);

  dim3 ag(HW_ / 128, B_, S);
  attn_kernel<<<ag, 256, LDS_TOTAL, stream>>>(Qt, Kt, Vn, a, out, Op, Ls, S);

  if (S > 1) {
    int nblk = (B_ * C_ * HW_ / 4) / 256;
    combine_kernel<<<nblk, 256, 0, stream>>>(Op, Ls, a, out, S);
  }
}